// Round 7
// baseline (261.806 us; speedup 1.0000x reference)
//
#include <hip/hip_runtime.h>
#include <hip/hip_bf16.h>

typedef unsigned short u16;
typedef __attribute__((ext_vector_type(8))) short bf16x8;
typedef __attribute__((ext_vector_type(4))) short short4v;
typedef __attribute__((ext_vector_type(4))) float floatx4;
typedef __attribute__((ext_vector_type(2))) unsigned uint2v;

__device__ __forceinline__ float bf2f(u16 u) {
    unsigned v = ((unsigned)u) << 16;
    return __builtin_bit_cast(float, v);
}
__device__ __forceinline__ u16 f2bf(float f) {
    unsigned u = __builtin_bit_cast(unsigned, f);
    u += 0x7fffu + ((u >> 16) & 1u);   // RNE
    return (u16)(u >> 16);
}

#define GLDS16(g, l)                                                             \
    __builtin_amdgcn_global_load_lds(                                            \
        (const __attribute__((address_space(1))) void*)(g),                      \
        (__attribute__((address_space(3))) void*)(l), 16, 0, 0)

// ---------------------------------------------------------------------------
// Fused prep: blocks [0,4096) cvt x->bf16 + zero oat; [4096,7168) Wqkv^T;
// [7168,8192) Wout^T.
// ---------------------------------------------------------------------------
__global__ __launch_bounds__(256) void prep(const float* __restrict__ x, u16* __restrict__ xb,
                                            float* __restrict__ oz,
                                            const float* __restrict__ Wqkv, u16* __restrict__ WqkvT,
                                            const float* __restrict__ Wout, u16* __restrict__ WoutT) {
    __shared__ u16 t[32][33];
    int blk = blockIdx.x;
    if (blk < 4096) {
        const int i = blk * 256 + threadIdx.x;
        const floatx4 v = ((const floatx4*)x)[i];
        short4v o;
#pragma unroll
        for (int j = 0; j < 4; ++j) o[j] = (short)f2bf(v[j]);
        ((short4v*)xb)[i] = o;
        const floatx4 z = {0.f, 0.f, 0.f, 0.f};
        ((floatx4*)oz)[i] = z;
        return;   // block-uniform: this block never reaches the barrier
    }
    const float* in; u16* out; int R, C, bx, by;
    if (blk < 4096 + 3072) { blk -= 4096; in = Wqkv; out = WqkvT; R = 1024; C = 3072; bx = blk % 96; by = blk / 96; }
    else                   { blk -= 7168; in = Wout; out = WoutT; R = 1024; C = 1024; bx = blk & 31; by = blk >> 5; }
    const int c0 = bx * 32, r0 = by * 32;
    const int xx = threadIdx.x & 31, yy = threadIdx.x >> 5;
#pragma unroll
    for (int i = 0; i < 32; i += 8) t[yy + i][xx] = f2bf(in[(size_t)(r0 + yy + i) * C + c0 + xx]);
    __syncthreads();
#pragma unroll
    for (int i = 0; i < 32; i += 8) out[(size_t)(c0 + yy + i) * R + r0 + xx] = t[xx][yy + i];
}

// ---------------------------------------------------------------------------
// m97-style GEMM: C[M,N] = A[M,K] @ Bt[N,K]^T (+bias), bf16 in, fp32 acc.
// Tile TM x 128, BK=32, block 256. VT: V-range blocks also emit vt = 0.125*V^T.
// ---------------------------------------------------------------------------
template <int TM, bool BIAS, typename OUT, bool VT>
__global__ __launch_bounds__(256) void gemm_bt(const u16* __restrict__ A, const u16* __restrict__ Bt,
                                               OUT* __restrict__ C, const float* __restrict__ bias,
                                               u16* __restrict__ vtp, int M, int N, int K) {
    constexpr int MI = TM / 32;
    __shared__ u16 sA[TM * 32];
    __shared__ u16 sB[128 * 32];
    const int tid = threadIdx.x;
    const int lane = tid & 63, wave = tid >> 6;
    const int l15 = lane & 15, quad = lane >> 4;
    const int row0 = blockIdx.y * TM, col0 = blockIdx.x * 128;
    const int wm = (wave & 1) * (TM / 2), wn = (wave >> 1) * 64;
    const int c_ = (tid & 3) << 3;
    floatx4 acc[MI][4] = {};
    for (int k0 = 0; k0 < K; k0 += 32) {
#pragma unroll
        for (int it = 0; it < 2; ++it) {
            const int idx = it * 256 + tid;
            const int r = idx >> 2;
            GLDS16(Bt + (size_t)(col0 + r) * K + k0 + c_, sB + idx * 8);
        }
#pragma unroll
        for (int it = 0; it < TM / 64; ++it) {
            const int idx = it * 256 + tid;
            const int r = idx >> 2;
            GLDS16(A + (size_t)(row0 + r) * K + k0 + c_, sA + idx * 8);
        }
        __syncthreads();
        bf16x8 af[MI], bfr[4];
#pragma unroll
        for (int i = 0; i < MI; ++i) af[i] = *(const bf16x8*)(sA + (wm + i * 16 + l15) * 32 + quad * 8);
#pragma unroll
        for (int j = 0; j < 4; ++j) bfr[j] = *(const bf16x8*)(sB + (wn + j * 16 + l15) * 32 + quad * 8);
#pragma unroll
        for (int i = 0; i < MI; ++i)
#pragma unroll
            for (int j = 0; j < 4; ++j)
                acc[i][j] = __builtin_amdgcn_mfma_f32_16x16x32_bf16(af[i], bfr[j], acc[i][j], 0, 0, 0);
        __syncthreads();
    }
#pragma unroll
    for (int i = 0; i < MI; ++i) {
#pragma unroll
        for (int j = 0; j < 4; ++j) {
            const int col = col0 + wn + j * 16 + l15;
            const int row = row0 + wm + i * 16 + quad * 4;
            const float b = BIAS ? bias[col] : 0.f;
            short4v pk;
#pragma unroll
            for (int r = 0; r < 4; ++r) {
                const float v = acc[i][j][r] + b;
                if constexpr (sizeof(OUT) == 2)
                    C[(size_t)(row + r) * N + col] = (OUT)f2bf(v);
                else
                    C[(size_t)(row + r) * N + col] = (OUT)v;
                if constexpr (VT) pk[r] = (short)f2bf(v * 0.125f);
            }
            if constexpr (VT) {
                if (col0 >= 2048) {   // V block: also emit transposed+scaled copy
                    const int bb = row >> 11, s = row & 2047;
                    const int hd = (col - 2048) >> 6, dh = col & 63;
                    *(short4v*)(vtp + ((size_t)(bb * 16 + hd) * 64 + dh) * 2048 + s) = pk;
                }
            }
        }
    }
}

// ---------------------------------------------------------------------------
// relu(S) pack: bf16 round-ties-away (+0x8000>>16), b64 store to LDS
// ---------------------------------------------------------------------------
__device__ __forceinline__ void pack_store(floatx4 s, u16* dst, bool diag, int kgb, int qg) {
    float v0 = fmaxf(s[0], 0.f), v1 = fmaxf(s[1], 0.f);
    float v2 = fmaxf(s[2], 0.f), v3 = fmaxf(s[3], 0.f);
    if (diag) {                      // wave-uniform branch: only diagonal chunks
        if (kgb + 0 > qg) v0 = 0.f;
        if (kgb + 1 > qg) v1 = 0.f;
        if (kgb + 2 > qg) v2 = 0.f;
        if (kgb + 3 > qg) v3 = 0.f;
    }
    uint2v p;
    p.x = ((__builtin_bit_cast(unsigned, v0) + 0x8000u) >> 16) |
          ((__builtin_bit_cast(unsigned, v1) + 0x8000u) & 0xffff0000u);
    p.y = ((__builtin_bit_cast(unsigned, v2) + 0x8000u) >> 16) |
          ((__builtin_bit_cast(unsigned, v3) + 0x8000u) & 0xffff0000u);
    *(uint2v*)dst = p;
}

// ---------------------------------------------------------------------------
// Causal ReLU attention, fat waves. Block = (bh, 4-chunk key slab s, q-group
// gq): 4 waves share staged K/V; wave w owns the FULL 64q x 64k tile for
// q-tile qt=4*gq+w, accumulating over the slab in regs. 4x MFMA per LDS read
// vs the R4 kernel (LDS-pipe was the bound). Same staged-LDS + double-barrier
// skeleton as the verified R4 kernel. Coverage: s<gq full slab, s==gq clipped
// diagonal; exact partition of kc in [0,qt]. Partials atomicAdd into oat.
// ---------------------------------------------------------------------------
__global__ __launch_bounds__(256) void relu_attn(const u16* __restrict__ h, const u16* __restrict__ vt,
                                                 float* __restrict__ o) {
    __shared__ u16 sK[64 * 72];        // [key][dh], stride 72
    __shared__ u16 sV[64 * 72];        // [dh][key], stride 72 (pre-scaled 0.125)
    __shared__ u16 sPall[4][64 * 34];  // per-wave [query][32-key], stride 34
    const int bid = blockIdx.x;
    const int bh = bid & 31;
    const int j = bid >> 5;            // [0,36)
    int s, gq;                         // slab, q-group (gq in [s,8))
    if      (j < 8)  { s = 0; gq = j; }
    else if (j < 15) { s = 1; gq = j - 7; }
    else if (j < 21) { s = 2; gq = j - 13; }
    else if (j < 26) { s = 3; gq = j - 18; }
    else if (j < 30) { s = 4; gq = j - 22; }
    else if (j < 33) { s = 5; gq = j - 25; }
    else if (j < 35) { s = 6; gq = j - 27; }
    else             { s = 7; gq = 7; }
    const int b = bh >> 4, hd = bh & 15;
    const int tid = threadIdx.x, lane = tid & 63, wave = tid >> 6;
    const int l15 = lane & 15, quad = lane >> 4;
    u16* sP = sPall[wave];
    const int qt = 4 * gq + wave;      // this wave's 64-query tile
    const int q0 = qt * 64;

    // Q B-fragments: 64 queries x 64 dh resident in regs (8 b128 global loads)
    bf16x8 qf[4][2];
    {
        const u16* qb = h + (size_t)(b * 2048 + q0) * 3072 + hd * 64;
#pragma unroll
        for (int qc = 0; qc < 4; ++qc)
#pragma unroll
            for (int ks = 0; ks < 2; ++ks)
                qf[qc][ks] = *(const bf16x8*)(qb + (size_t)(qc * 16 + l15) * 3072 + ks * 32 + quad * 8);
    }

    floatx4 acc[4][4] = {};
    const u16* kbase = h + (size_t)(b * 2048) * 3072 + 1024 + hd * 64;
    const u16* vbase = vt + (size_t)bh * 64 * 2048;
    const int sr = tid >> 3;           // staging row 0..31 (+it*32)
    const int sc = (tid & 7) << 3;     // staging col 0..56

    for (int kc = 4 * s; kc <= 4 * s + 3; ++kc) {
        const int c0 = kc * 64;
        // stage K [64k][64dh] and V^T [64dh][64k] (whole block cooperates)
#pragma unroll
        for (int it = 0; it < 2; ++it) {
            const int r = it * 32 + sr;
            bf16x8 kv = *(const bf16x8*)(kbase + (size_t)(c0 + r) * 3072 + sc);
            bf16x8 vv = *(const bf16x8*)(vbase + (size_t)r * 2048 + c0 + sc);
            *(bf16x8*)(sK + r * 72 + sc) = kv;
            *(bf16x8*)(sV + r * 72 + sc) = vv;
        }
        __syncthreads();
        if (kc <= qt) {                // wave-level causal clip (diag group only)
            const bool diag = (kc == qt);
            const floatx4 z = {0.f, 0.f, 0.f, 0.f};
#pragma unroll
            for (int kb = 0; kb < 2; ++kb) {
                // S^T = K.Q^T over 32 keys x 64 queries; pack -> sP
#pragma unroll
                for (int mt = 0; mt < 2; ++mt) {
                    const bf16x8 kf0 = *(const bf16x8*)(sK + (kb * 32 + mt * 16 + l15) * 72 + quad * 8);
                    const bf16x8 kf1 = *(const bf16x8*)(sK + (kb * 32 + mt * 16 + l15) * 72 + 32 + quad * 8);
#pragma unroll
                    for (int qc = 0; qc < 4; ++qc) {
                        floatx4 sv_ = __builtin_amdgcn_mfma_f32_16x16x32_bf16(kf0, qf[qc][0], z, 0, 0, 0);
                        sv_ = __builtin_amdgcn_mfma_f32_16x16x32_bf16(kf1, qf[qc][1], sv_, 0, 0, 0);
                        pack_store(sv_, sP + (qc * 16 + l15) * 34 + mt * 16 + quad * 4,
                                   diag, kb * 32 + mt * 16 + quad * 4, qc * 16 + l15);
                    }
                }
                // PV: O += P.V (wave-private sP; DS in-order within a wave)
                bf16x8 vf[4], pf[4];
#pragma unroll
                for (int nt = 0; nt < 4; ++nt)
                    vf[nt] = *(const bf16x8*)(sV + (nt * 16 + l15) * 72 + kb * 32 + quad * 8);
#pragma unroll
                for (int qr = 0; qr < 4; ++qr)
                    pf[qr] = *(const bf16x8*)(sP + (qr * 16 + l15) * 34 + quad * 8);
#pragma unroll
                for (int qr = 0; qr < 4; ++qr)
#pragma unroll
                    for (int nt = 0; nt < 4; ++nt)
                        acc[qr][nt] = __builtin_amdgcn_mfma_f32_16x16x32_bf16(pf[qr], vf[nt], acc[qr][nt], 0, 0, 0);
            }
        }
        __syncthreads();
    }
    // epilogue: atomic-accumulate partials into fp32 o [B,S,D]
#pragma unroll
    for (int qr = 0; qr < 4; ++qr) {
#pragma unroll
        for (int nt = 0; nt < 4; ++nt) {
            const int col = hd * 64 + nt * 16 + l15;
            const int row = b * 2048 + q0 + qr * 16 + quad * 4;
#pragma unroll
            for (int r = 0; r < 4; ++r)
                atomicAdd(&o[(size_t)(row + r) * 1024 + col], acc[qr][nt][r]);
        }
    }
}

// ---------------------------------------------------------------------------
// Gated RMSNorm: one block per row of o [4096][1024] fp32 -> bf16
// ---------------------------------------------------------------------------
__global__ __launch_bounds__(256) void rms_gate(const float* __restrict__ o, const float* __restrict__ scale,
                                                const float* __restrict__ gate, u16* __restrict__ out) {
    const int row = blockIdx.x;
    const int tid = threadIdx.x;
    const floatx4* op = (const floatx4*)(o + (size_t)row * 1024);
    floatx4 v = op[tid];
    float ss = v[0] * v[0] + v[1] * v[1] + v[2] * v[2] + v[3] * v[3];
#pragma unroll
    for (int m = 32; m >= 1; m >>= 1) ss += __shfl_xor(ss, m, 64);
    __shared__ float red[4];
    if ((tid & 63) == 0) red[tid >> 6] = ss;
    __syncthreads();
    const float ms = (red[0] + red[1] + red[2] + red[3]) * (1.0f / 1024.0f);
    const float inv = rsqrtf(ms + 1e-7f);
    const int c = tid * 4;
#pragma unroll
    for (int j = 0; j < 4; ++j) {
        const float s = scale[c + j];
        const float g = gate[c + j];
        const float x = v[j];
        const float sig = 1.0f / (1.0f + __expf(-g * x));
        out[(size_t)row * 1024 + c + j] = f2bf(s * x * inv * sig);
    }
}

// ---------------------------------------------------------------------------
extern "C" void kernel_launch(void* const* d_in, const int* in_sizes, int n_in,
                              void* d_out, int out_size, void* d_ws, size_t ws_size,
                              hipStream_t stream) {
    const float* x     = (const float*)d_in[0];   // [2,2048,1024] fp32
    // d_in[1] = mem_mask: structurally causal, applied analytically
    const float* Wqkv  = (const float*)d_in[2];   // [1024,3072] fp32
    const float* Wout  = (const float*)d_in[3];   // [1024,1024] fp32
    const float* bout  = (const float*)d_in[4];   // [1024] fp32
    const float* scale = (const float*)d_in[5];   // [1024] fp32
    const float* gate  = (const float*)d_in[6];   // [1024] fp32
    float* out = (float*)d_out;                   // [2,2048,1024] fp32

    char* p = (char*)d_ws;
    u16* xb    = (u16*)p; p += (size_t)4096 * 1024 * 2;    // x in bf16
    u16* h     = (u16*)p; p += (size_t)4096 * 3072 * 2;    // qkv projection (bf16)
    u16* vt    = (u16*)p; p += (size_t)32 * 64 * 2048 * 2; // V^T [bh][dh][s], pre-scaled 0.125
    u16* WqkvT = (u16*)p; p += (size_t)3072 * 1024 * 2;
    u16* WoutT = (u16*)p; p += (size_t)1024 * 1024 * 2;
    float* oat = (float*)p; p += (size_t)4096 * 1024 * 4;  // attention out fp32 (atomic acc)
    u16* onorm = (u16*)p; p += (size_t)4096 * 1024 * 2;

    prep<<<8192, 256, 0, stream>>>(x, xb, oat, Wqkv, WqkvT, Wout, WoutT);
    gemm_bt<128, false, u16, true><<<dim3(24, 32), 256, 0, stream>>>(xb, WqkvT, h, nullptr, vt, 4096, 3072, 1024);
    relu_attn<<<1152, 256, 0, stream>>>(h, vt, oat);
    rms_gate<<<4096, 256, 0, stream>>>(oat, scale, gate, onorm);
    gemm_bt<64, true, float, false><<<dim3(8, 64), 256, 0, stream>>>(onorm, WoutT, out, bout, nullptr, 4096, 1024, 1024);
}

// Round 8
// 218.712 us; speedup vs baseline: 1.1970x; 1.1970x over previous
//
#include <hip/hip_runtime.h>
#include <hip/hip_bf16.h>

typedef unsigned short u16;
typedef __attribute__((ext_vector_type(8))) short bf16x8;
typedef __attribute__((ext_vector_type(4))) short short4v;
typedef __attribute__((ext_vector_type(4))) float floatx4;
typedef __attribute__((ext_vector_type(2))) unsigned uint2v;

__device__ __forceinline__ float bf2f(u16 u) {
    unsigned v = ((unsigned)u) << 16;
    return __builtin_bit_cast(float, v);
}
__device__ __forceinline__ u16 f2bf(float f) {
    unsigned u = __builtin_bit_cast(unsigned, f);
    u += 0x7fffu + ((u >> 16) & 1u);   // RNE
    return (u16)(u >> 16);
}

#define GLDS16(g, l)                                                             \
    __builtin_amdgcn_global_load_lds(                                            \
        (const __attribute__((address_space(1))) void*)(g),                      \
        (__attribute__((address_space(3))) void*)(l), 16, 0, 0)

// ---------------------------------------------------------------------------
// Fused prep: blocks [0,4096) cvt x->bf16; [4096,7168) Wqkv^T; [7168,8192) Wout^T.
// (oat zero-init removed: R3-style attn fully overwrites it with plain stores)
// ---------------------------------------------------------------------------
__global__ __launch_bounds__(256) void prep(const float* __restrict__ x, u16* __restrict__ xb,
                                            const float* __restrict__ Wqkv, u16* __restrict__ WqkvT,
                                            const float* __restrict__ Wout, u16* __restrict__ WoutT) {
    __shared__ u16 t[32][33];
    int blk = blockIdx.x;
    if (blk < 4096) {
        const int i = blk * 256 + threadIdx.x;
        const floatx4 v = ((const floatx4*)x)[i];
        short4v o;
#pragma unroll
        for (int j = 0; j < 4; ++j) o[j] = (short)f2bf(v[j]);
        ((short4v*)xb)[i] = o;
        return;   // block-uniform: this block never reaches the barrier
    }
    const float* in; u16* out; int R, C, bx, by;
    if (blk < 4096 + 3072) { blk -= 4096; in = Wqkv; out = WqkvT; R = 1024; C = 3072; bx = blk % 96; by = blk / 96; }
    else                   { blk -= 7168; in = Wout; out = WoutT; R = 1024; C = 1024; bx = blk & 31; by = blk >> 5; }
    const int c0 = bx * 32, r0 = by * 32;
    const int xx = threadIdx.x & 31, yy = threadIdx.x >> 5;
#pragma unroll
    for (int i = 0; i < 32; i += 8) t[yy + i][xx] = f2bf(in[(size_t)(r0 + yy + i) * C + c0 + xx]);
    __syncthreads();
#pragma unroll
    for (int i = 0; i < 32; i += 8) out[(size_t)(c0 + yy + i) * R + r0 + xx] = t[xx][yy + i];
}

// ---------------------------------------------------------------------------
// m97-style GEMM: C[M,N] = A[M,K] @ Bt[N,K]^T (+bias), bf16 in, fp32 acc.
// Tile TM x 128, BK=32, block 256. VT: V-range blocks also emit vt = 0.125*V^T.
// ---------------------------------------------------------------------------
template <int TM, bool BIAS, typename OUT, bool VT>
__global__ __launch_bounds__(256) void gemm_bt(const u16* __restrict__ A, const u16* __restrict__ Bt,
                                               OUT* __restrict__ C, const float* __restrict__ bias,
                                               u16* __restrict__ vtp, int M, int N, int K) {
    constexpr int MI = TM / 32;
    __shared__ u16 sA[TM * 32];
    __shared__ u16 sB[128 * 32];
    const int tid = threadIdx.x;
    const int lane = tid & 63, wave = tid >> 6;
    const int l15 = lane & 15, quad = lane >> 4;
    const int row0 = blockIdx.y * TM, col0 = blockIdx.x * 128;
    const int wm = (wave & 1) * (TM / 2), wn = (wave >> 1) * 64;
    const int c_ = (tid & 3) << 3;
    floatx4 acc[MI][4] = {};
    for (int k0 = 0; k0 < K; k0 += 32) {
#pragma unroll
        for (int it = 0; it < 2; ++it) {
            const int idx = it * 256 + tid;
            const int r = idx >> 2;
            GLDS16(Bt + (size_t)(col0 + r) * K + k0 + c_, sB + idx * 8);
        }
#pragma unroll
        for (int it = 0; it < TM / 64; ++it) {
            const int idx = it * 256 + tid;
            const int r = idx >> 2;
            GLDS16(A + (size_t)(row0 + r) * K + k0 + c_, sA + idx * 8);
        }
        __syncthreads();
        bf16x8 af[MI], bfr[4];
#pragma unroll
        for (int i = 0; i < MI; ++i) af[i] = *(const bf16x8*)(sA + (wm + i * 16 + l15) * 32 + quad * 8);
#pragma unroll
        for (int j = 0; j < 4; ++j) bfr[j] = *(const bf16x8*)(sB + (wn + j * 16 + l15) * 32 + quad * 8);
#pragma unroll
        for (int i = 0; i < MI; ++i)
#pragma unroll
            for (int j = 0; j < 4; ++j)
                acc[i][j] = __builtin_amdgcn_mfma_f32_16x16x32_bf16(af[i], bfr[j], acc[i][j], 0, 0, 0);
        __syncthreads();
    }
#pragma unroll
    for (int i = 0; i < MI; ++i) {
#pragma unroll
        for (int j = 0; j < 4; ++j) {
            const int col = col0 + wn + j * 16 + l15;
            const int row = row0 + wm + i * 16 + quad * 4;
            const float b = BIAS ? bias[col] : 0.f;
            short4v pk;
#pragma unroll
            for (int r = 0; r < 4; ++r) {
                const float v = acc[i][j][r] + b;
                if constexpr (sizeof(OUT) == 2)
                    C[(size_t)(row + r) * N + col] = (OUT)f2bf(v);
                else
                    C[(size_t)(row + r) * N + col] = (OUT)v;
                if constexpr (VT) pk[r] = (short)f2bf(v * 0.125f);
            }
            if constexpr (VT) {
                if (col0 >= 2048) {   // V block: also emit transposed+scaled copy
                    const int bb = row >> 11, s = row & 2047;
                    const int hd = (col - 2048) >> 6, dh = col & 63;
                    *(short4v*)(vtp + ((size_t)(bb * 16 + hd) * 64 + dh) * 2048 + s) = pk;
                }
            }
        }
    }
}

// ---------------------------------------------------------------------------
// relu(S) pack: bf16 round-ties-away (+0x8000>>16), b64 store to LDS
// ---------------------------------------------------------------------------
__device__ __forceinline__ void pack_store(floatx4 s, u16* dst, bool diag, int kgb, int qg) {
    float v0 = fmaxf(s[0], 0.f), v1 = fmaxf(s[1], 0.f);
    float v2 = fmaxf(s[2], 0.f), v3 = fmaxf(s[3], 0.f);
    if (diag) {                      // wave-uniform branch: only diagonal chunks
        if (kgb + 0 > qg) v0 = 0.f;
        if (kgb + 1 > qg) v1 = 0.f;
        if (kgb + 2 > qg) v2 = 0.f;
        if (kgb + 3 > qg) v3 = 0.f;
    }
    uint2v p;
    p.x = ((__builtin_bit_cast(unsigned, v0) + 0x8000u) >> 16) |
          ((__builtin_bit_cast(unsigned, v1) + 0x8000u) & 0xffff0000u);
    p.y = ((__builtin_bit_cast(unsigned, v2) + 0x8000u) >> 16) |
          ((__builtin_bit_cast(unsigned, v3) + 0x8000u) & 0xffff0000u);
    *(uint2v*)dst = p;
}

// ---------------------------------------------------------------------------
// Causal ReLU attention, tile-paired for uniform work (R3-proven kernel).
// Block = (bh, pair pr): light q-tile qtl=pr (64 q), heavy qth=31-pr (64 q).
// Loop key chunks kc=0..qth; both tiles share the staged K/V chunk while the
// light tile is active (kc<=qtl). MFMA count/wave = 264 for every block.
// ---------------------------------------------------------------------------
__global__ __launch_bounds__(256) void relu_attn(const u16* __restrict__ h, const u16* __restrict__ vt,
                                                 float* __restrict__ o) {
    __shared__ u16 sK[64 * 72];    // [key][dh], stride 72
    __shared__ u16 sV[64 * 72];    // [dh][key], stride 72 (pre-scaled by 0.125)
    __shared__ u16 sP[128 * 72];   // rows 0..63 light, 64..127 heavy
    const int bid = blockIdx.x;
    const int pr = bid >> 5;            // 0 = heaviest pair, dispatched first
    const int bh = bid & 31;
    const int b = bh >> 4, hd = bh & 15;
    const int qtl = pr, qth = 31 - pr;  // 64-query tile indices
    const int tid = threadIdx.x, lane = tid & 63, wave = tid >> 6;
    const int l15 = lane & 15, quad = lane >> 4;

    // Q B-fragments (wave owns 16 queries per tile), resident all kernel
    bf16x8 qfl[2], qfh[2];
    {
        const u16* ql = h + (size_t)(b * 2048 + qtl * 64 + wave * 16 + l15) * 3072 + hd * 64;
        const u16* qh = h + (size_t)(b * 2048 + qth * 64 + wave * 16 + l15) * 3072 + hd * 64;
#pragma unroll
        for (int ks = 0; ks < 2; ++ks) {
            qfl[ks] = *(const bf16x8*)(ql + ks * 32 + quad * 8);
            qfh[ks] = *(const bf16x8*)(qh + ks * 32 + quad * 8);
        }
    }

    floatx4 accl[4] = {}, acch[4] = {};
    const u16* kbase = h + (size_t)(b * 2048) * 3072 + 1024 + hd * 64;
    const u16* vbase = vt + (size_t)bh * 64 * 2048;
    const int sr = tid >> 3;           // staging row 0..31 (+it*32)
    const int sc = (tid & 7) << 3;     // staging col 0..56
    const int qg = wave * 16 + l15;    // within-tile query (for diag mask)

    for (int kc = 0; kc <= qth; ++kc) {
        const int c0 = kc * 64;
#pragma unroll
        for (int it = 0; it < 2; ++it) {
            const int r = it * 32 + sr;
            bf16x8 kv = *(const bf16x8*)(kbase + (size_t)(c0 + r) * 3072 + sc);
            bf16x8 vv = *(const bf16x8*)(vbase + (size_t)r * 2048 + c0 + sc);
            *(bf16x8*)(sK + r * 72 + sc) = kv;
            *(bf16x8*)(sV + r * 72 + sc) = vv;
        }
        __syncthreads();
        const bool lact = (kc <= qtl);
        const floatx4 z = {0.f, 0.f, 0.f, 0.f};
        // S^T = K·Q^T; pack relu -> sP [query][key] (wave-private rows)
#pragma unroll
        for (int mt = 0; mt < 4; ++mt) {
            const bf16x8 kf0 = *(const bf16x8*)(sK + (mt * 16 + l15) * 72 + quad * 8);
            const bf16x8 kf1 = *(const bf16x8*)(sK + (mt * 16 + l15) * 72 + 32 + quad * 8);
            const int kgb = mt * 16 + quad * 4;
            floatx4 s = __builtin_amdgcn_mfma_f32_16x16x32_bf16(kf0, qfh[0], z, 0, 0, 0);
            s = __builtin_amdgcn_mfma_f32_16x16x32_bf16(kf1, qfh[1], s, 0, 0, 0);
            pack_store(s, sP + (size_t)(64 + qg) * 72 + kgb, kc == qth, kgb, qg);
            if (lact) {
                floatx4 t = __builtin_amdgcn_mfma_f32_16x16x32_bf16(kf0, qfl[0], z, 0, 0, 0);
                t = __builtin_amdgcn_mfma_f32_16x16x32_bf16(kf1, qfl[1], t, 0, 0, 0);
                pack_store(t, sP + (size_t)qg * 72 + kgb, kc == qtl, kgb, qg);
            }
        }
        // PV: O += P·V (wave reads only its own sP rows -> no extra barrier)
#pragma unroll
        for (int kb = 0; kb < 2; ++kb) {
            const bf16x8 pfh = *(const bf16x8*)(sP + (size_t)(64 + wave * 16 + l15) * 72 + kb * 32 + quad * 8);
#pragma unroll
            for (int nt = 0; nt < 4; ++nt) {
                const bf16x8 vf = *(const bf16x8*)(sV + (nt * 16 + l15) * 72 + kb * 32 + quad * 8);
                acch[nt] = __builtin_amdgcn_mfma_f32_16x16x32_bf16(pfh, vf, acch[nt], 0, 0, 0);
                if (lact) {
                    const bf16x8 pfl = *(const bf16x8*)(sP + (size_t)(wave * 16 + l15) * 72 + kb * 32 + quad * 8);
                    accl[nt] = __builtin_amdgcn_mfma_f32_16x16x32_bf16(pfl, vf, accl[nt], 0, 0, 0);
                }
            }
        }
        __syncthreads();
    }
    // epilogue: write combined-head fp32 o [B,S,D] (full overwrite, no atomics)
#pragma unroll
    for (int nt = 0; nt < 4; ++nt) {
        const int col = hd * 64 + nt * 16 + l15;
        const int rl = qtl * 64 + wave * 16 + quad * 4;
        const int rh = qth * 64 + wave * 16 + quad * 4;
#pragma unroll
        for (int r = 0; r < 4; ++r) {
            o[(size_t)(b * 2048 + rl + r) * 1024 + col] = accl[nt][r];
            o[(size_t)(b * 2048 + rh + r) * 1024 + col] = acch[nt][r];
        }
    }
}

// ---------------------------------------------------------------------------
// Gated RMSNorm: one block per row of o [4096][1024] fp32 -> bf16
// ---------------------------------------------------------------------------
__global__ __launch_bounds__(256) void rms_gate(const float* __restrict__ o, const float* __restrict__ scale,
                                                const float* __restrict__ gate, u16* __restrict__ out) {
    const int row = blockIdx.x;
    const int tid = threadIdx.x;
    const floatx4* op = (const floatx4*)(o + (size_t)row * 1024);
    floatx4 v = op[tid];
    float ss = v[0] * v[0] + v[1] * v[1] + v[2] * v[2] + v[3] * v[3];
#pragma unroll
    for (int m = 32; m >= 1; m >>= 1) ss += __shfl_xor(ss, m, 64);
    __shared__ float red[4];
    if ((tid & 63) == 0) red[tid >> 6] = ss;
    __syncthreads();
    const float ms = (red[0] + red[1] + red[2] + red[3]) * (1.0f / 1024.0f);
    const float inv = rsqrtf(ms + 1e-7f);
    const int c = tid * 4;
#pragma unroll
    for (int j = 0; j < 4; ++j) {
        const float s = scale[c + j];
        const float g = gate[c + j];
        const float x = v[j];
        const float sig = 1.0f / (1.0f + __expf(-g * x));
        out[(size_t)row * 1024 + c + j] = f2bf(s * x * inv * sig);
    }
}

// ---------------------------------------------------------------------------
extern "C" void kernel_launch(void* const* d_in, const int* in_sizes, int n_in,
                              void* d_out, int out_size, void* d_ws, size_t ws_size,
                              hipStream_t stream) {
    const float* x     = (const float*)d_in[0];   // [2,2048,1024] fp32
    // d_in[1] = mem_mask: structurally causal, applied analytically
    const float* Wqkv  = (const float*)d_in[2];   // [1024,3072] fp32
    const float* Wout  = (const float*)d_in[3];   // [1024,1024] fp32
    const float* bout  = (const float*)d_in[4];   // [1024] fp32
    const float* scale = (const float*)d_in[5];   // [1024] fp32
    const float* gate  = (const float*)d_in[6];   // [1024] fp32
    float* out = (float*)d_out;                   // [2,2048,1024] fp32

    char* p = (char*)d_ws;
    u16* xb    = (u16*)p; p += (size_t)4096 * 1024 * 2;    // x in bf16
    u16* h     = (u16*)p; p += (size_t)4096 * 3072 * 2;    // qkv projection (bf16)
    u16* vt    = (u16*)p; p += (size_t)32 * 64 * 2048 * 2; // V^T [bh][dh][s], pre-scaled 0.125
    u16* WqkvT = (u16*)p; p += (size_t)3072 * 1024 * 2;
    u16* WoutT = (u16*)p; p += (size_t)1024 * 1024 * 2;
    float* oat = (float*)p; p += (size_t)4096 * 1024 * 4;  // attention out fp32
    u16* onorm = (u16*)p; p += (size_t)4096 * 1024 * 2;

    prep<<<8192, 256, 0, stream>>>(x, xb, Wqkv, WqkvT, Wout, WoutT);
    gemm_bt<128, false, u16, true><<<dim3(24, 32), 256, 0, stream>>>(xb, WqkvT, h, nullptr, vt, 4096, 3072, 1024);
    relu_attn<<<512, 256, 0, stream>>>(h, vt, oat);
    rms_gate<<<4096, 256, 0, stream>>>(oat, scale, gate, onorm);
    gemm_bt<64, true, float, false><<<dim3(8, 64), 256, 0, stream>>>(onorm, WoutT, out, bout, nullptr, 4096, 1024, 1024);
}

// Round 9
// 217.576 us; speedup vs baseline: 1.2033x; 1.0052x over previous
//
#include <hip/hip_runtime.h>
#include <hip/hip_bf16.h>

typedef unsigned short u16;
typedef __attribute__((ext_vector_type(8))) short bf16x8;
typedef __attribute__((ext_vector_type(4))) short short4v;
typedef __attribute__((ext_vector_type(4))) float floatx4;
typedef __attribute__((ext_vector_type(2))) unsigned uint2v;

__device__ __forceinline__ float bf2f(u16 u) {
    unsigned v = ((unsigned)u) << 16;
    return __builtin_bit_cast(float, v);
}
__device__ __forceinline__ u16 f2bf(float f) {
    unsigned u = __builtin_bit_cast(unsigned, f);
    u += 0x7fffu + ((u >> 16) & 1u);   // RNE
    return (u16)(u >> 16);
}

#define GLDS16(g, l)                                                             \
    __builtin_amdgcn_global_load_lds(                                            \
        (const __attribute__((address_space(1))) void*)(g),                      \
        (__attribute__((address_space(3))) void*)(l), 16, 0, 0)

// ---------------------------------------------------------------------------
// Fused prep: blocks [0,4096) cvt x->bf16; [4096,7168) Wqkv^T; [7168,8192) Wout^T.
// ---------------------------------------------------------------------------
__global__ __launch_bounds__(256) void prep(const float* __restrict__ x, u16* __restrict__ xb,
                                            const float* __restrict__ Wqkv, u16* __restrict__ WqkvT,
                                            const float* __restrict__ Wout, u16* __restrict__ WoutT) {
    __shared__ u16 t[32][33];
    int blk = blockIdx.x;
    if (blk < 4096) {
        const int i = blk * 256 + threadIdx.x;
        const floatx4 v = ((const floatx4*)x)[i];
        short4v o;
#pragma unroll
        for (int j = 0; j < 4; ++j) o[j] = (short)f2bf(v[j]);
        ((short4v*)xb)[i] = o;
        return;   // block-uniform: this block never reaches the barrier
    }
    const float* in; u16* out; int R, C, bx, by;
    if (blk < 4096 + 3072) { blk -= 4096; in = Wqkv; out = WqkvT; R = 1024; C = 3072; bx = blk % 96; by = blk / 96; }
    else                   { blk -= 7168; in = Wout; out = WoutT; R = 1024; C = 1024; bx = blk & 31; by = blk >> 5; }
    const int c0 = bx * 32, r0 = by * 32;
    const int xx = threadIdx.x & 31, yy = threadIdx.x >> 5;
#pragma unroll
    for (int i = 0; i < 32; i += 8) t[yy + i][xx] = f2bf(in[(size_t)(r0 + yy + i) * C + c0 + xx]);
    __syncthreads();
#pragma unroll
    for (int i = 0; i < 32; i += 8) out[(size_t)(c0 + yy + i) * R + r0 + xx] = t[xx][yy + i];
}

// ---------------------------------------------------------------------------
// m97-style GEMM: C[M,N] = A[M,K] @ Bt[N,K]^T (+bias), bf16 in, fp32 acc.
// Tile TM x 128, BK=32, block 256. VT: V-range blocks also emit vt = 0.125*V^T.
// ---------------------------------------------------------------------------
template <int TM, bool BIAS, typename OUT, bool VT>
__global__ __launch_bounds__(256) void gemm_bt(const u16* __restrict__ A, const u16* __restrict__ Bt,
                                               OUT* __restrict__ C, const float* __restrict__ bias,
                                               u16* __restrict__ vtp, int M, int N, int K) {
    constexpr int MI = TM / 32;
    __shared__ u16 sA[TM * 32];
    __shared__ u16 sB[128 * 32];
    const int tid = threadIdx.x;
    const int lane = tid & 63, wave = tid >> 6;
    const int l15 = lane & 15, quad = lane >> 4;
    const int row0 = blockIdx.y * TM, col0 = blockIdx.x * 128;
    const int wm = (wave & 1) * (TM / 2), wn = (wave >> 1) * 64;
    const int c_ = (tid & 3) << 3;
    floatx4 acc[MI][4] = {};
    for (int k0 = 0; k0 < K; k0 += 32) {
#pragma unroll
        for (int it = 0; it < 2; ++it) {
            const int idx = it * 256 + tid;
            const int r = idx >> 2;
            GLDS16(Bt + (size_t)(col0 + r) * K + k0 + c_, sB + idx * 8);
        }
#pragma unroll
        for (int it = 0; it < TM / 64; ++it) {
            const int idx = it * 256 + tid;
            const int r = idx >> 2;
            GLDS16(A + (size_t)(row0 + r) * K + k0 + c_, sA + idx * 8);
        }
        __syncthreads();
        bf16x8 af[MI], bfr[4];
#pragma unroll
        for (int i = 0; i < MI; ++i) af[i] = *(const bf16x8*)(sA + (wm + i * 16 + l15) * 32 + quad * 8);
#pragma unroll
        for (int j = 0; j < 4; ++j) bfr[j] = *(const bf16x8*)(sB + (wn + j * 16 + l15) * 32 + quad * 8);
#pragma unroll
        for (int i = 0; i < MI; ++i)
#pragma unroll
            for (int j = 0; j < 4; ++j)
                acc[i][j] = __builtin_amdgcn_mfma_f32_16x16x32_bf16(af[i], bfr[j], acc[i][j], 0, 0, 0);
        __syncthreads();
    }
#pragma unroll
    for (int i = 0; i < MI; ++i) {
#pragma unroll
        for (int j = 0; j < 4; ++j) {
            const int col = col0 + wn + j * 16 + l15;
            const int row = row0 + wm + i * 16 + quad * 4;
            const float b = BIAS ? bias[col] : 0.f;
            short4v pk;
#pragma unroll
            for (int r = 0; r < 4; ++r) {
                const float v = acc[i][j][r] + b;
                if constexpr (sizeof(OUT) == 2)
                    C[(size_t)(row + r) * N + col] = (OUT)f2bf(v);
                else
                    C[(size_t)(row + r) * N + col] = (OUT)v;
                if constexpr (VT) pk[r] = (short)f2bf(v * 0.125f);
            }
            if constexpr (VT) {
                if (col0 >= 2048) {   // V block: also emit transposed+scaled copy
                    const int bb = row >> 11, s = row & 2047;
                    const int hd = (col - 2048) >> 6, dh = col & 63;
                    *(short4v*)(vtp + ((size_t)(bb * 16 + hd) * 64 + dh) * 2048 + s) = pk;
                }
            }
        }
    }
}

// ---------------------------------------------------------------------------
// relu(S) pack: bf16 round-ties-away (+0x8000>>16), b64 store to LDS
// ---------------------------------------------------------------------------
__device__ __forceinline__ void pack_store(floatx4 s, u16* dst, bool diag, int kgb, int qg) {
    float v0 = fmaxf(s[0], 0.f), v1 = fmaxf(s[1], 0.f);
    float v2 = fmaxf(s[2], 0.f), v3 = fmaxf(s[3], 0.f);
    if (diag) {                      // wave-uniform branch: only diagonal chunks
        if (kgb + 0 > qg) v0 = 0.f;
        if (kgb + 1 > qg) v1 = 0.f;
        if (kgb + 2 > qg) v2 = 0.f;
        if (kgb + 3 > qg) v3 = 0.f;
    }
    uint2v p;
    p.x = ((__builtin_bit_cast(unsigned, v0) + 0x8000u) >> 16) |
          ((__builtin_bit_cast(unsigned, v1) + 0x8000u) & 0xffff0000u);
    p.y = ((__builtin_bit_cast(unsigned, v2) + 0x8000u) >> 16) |
          ((__builtin_bit_cast(unsigned, v3) + 0x8000u) & 0xffff0000u);
    *(uint2v*)dst = p;
}

// ---------------------------------------------------------------------------
// Causal ReLU attention, tile-paired (R3 skeleton) + async double-buffered
// K/V staging via global_load_lds. Block = (bh, pair pr): light tile qtl=pr,
// heavy qth=31-pr. Chunk kc+1 is DMA'd into the alternate LDS buffer while
// chunk kc computes; the barrier's vmcnt(0) drain lands after compute,
// hiding global latency. XOR swizzle (blk ^= row&7) replaces padding since
// GLDS requires lane-linear LDS destinations; all frag reads are <=2-way.
// ---------------------------------------------------------------------------
__global__ __launch_bounds__(256) void relu_attn(const u16* __restrict__ h, const u16* __restrict__ vt,
                                                 float* __restrict__ o) {
    __shared__ u16 sK[2][64 * 64];  // [buf][key][dh], swizzled 16B blocks
    __shared__ u16 sV[2][64 * 64];  // [buf][dh][key], swizzled (pre-scaled 0.125)
    __shared__ u16 sP[128 * 72];    // rows 0..63 light, 64..127 heavy (stride 72)
    const int bid = blockIdx.x;
    const int pr = bid >> 5;            // 0 = heaviest pair, dispatched first
    const int bh = bid & 31;
    const int b = bh >> 4, hd = bh & 15;
    const int qtl = pr, qth = 31 - pr;  // 64-query tile indices
    const int tid = threadIdx.x, lane = tid & 63, wave = tid >> 6;
    const int l15 = lane & 15, quad = lane >> 4;
    const int swz = l15 & 7;

    // Q B-fragments (wave owns 16 queries per tile), resident all kernel
    bf16x8 qfl[2], qfh[2];
    {
        const u16* ql = h + (size_t)(b * 2048 + qtl * 64 + wave * 16 + l15) * 3072 + hd * 64;
        const u16* qh = h + (size_t)(b * 2048 + qth * 64 + wave * 16 + l15) * 3072 + hd * 64;
#pragma unroll
        for (int ks = 0; ks < 2; ++ks) {
            qfl[ks] = *(const bf16x8*)(ql + ks * 32 + quad * 8);
            qfh[ks] = *(const bf16x8*)(qh + ks * 32 + quad * 8);
        }
    }

    floatx4 accl[4] = {}, acch[4] = {};
    const u16* kbase = h + (size_t)(b * 2048) * 3072 + 1024 + hd * 64;
    const u16* vbase = vt + (size_t)bh * 64 * 2048;
    const int qg = wave * 16 + l15;    // within-tile query (for diag mask)

    // async stage of one 64-key chunk into buffer bufi (4 GLDS16/thread)
    auto stage = [&](int kc, int bufi) {
#pragma unroll
        for (int it = 0; it < 2; ++it) {
            const int idx = it * 256 + tid;
            const int r = idx >> 3;                 // row 0..63
            const int cg = (idx & 7) ^ (r & 7);     // swizzled 16B block
            GLDS16(kbase + (size_t)(kc * 64 + r) * 3072 + cg * 8, &sK[bufi][idx * 8]);
            GLDS16(vbase + (size_t)r * 2048 + kc * 64 + cg * 8, &sV[bufi][idx * 8]);
        }
    };

    stage(0, 0);
    __syncthreads();                   // drains vmcnt: buf0 ready

    for (int kc = 0; kc <= qth; ++kc) {
        const int cur = kc & 1;
        if (kc < qth) stage(kc + 1, cur ^ 1);   // fly during compute
        const u16* sKb = sK[cur];
        const u16* sVb = sV[cur];
        const bool lact = (kc <= qtl);
        const floatx4 z = {0.f, 0.f, 0.f, 0.f};
        const int c0 = kc * 64;
        // S^T = K·Q^T; pack relu -> sP [query][key] (wave-private rows)
#pragma unroll
        for (int mt = 0; mt < 4; ++mt) {
            const int R = mt * 16 + l15;
            const int cq = quad ^ swz;
            const bf16x8 kf0 = *(const bf16x8*)(sKb + R * 64 + cq * 8);
            const bf16x8 kf1 = *(const bf16x8*)(sKb + R * 64 + (cq ^ 4) * 8);
            const int kgb = mt * 16 + quad * 4;
            floatx4 s = __builtin_amdgcn_mfma_f32_16x16x32_bf16(kf0, qfh[0], z, 0, 0, 0);
            s = __builtin_amdgcn_mfma_f32_16x16x32_bf16(kf1, qfh[1], s, 0, 0, 0);
            pack_store(s, sP + (size_t)(64 + qg) * 72 + kgb, kc == qth, kgb, qg);
            if (lact) {
                floatx4 t = __builtin_amdgcn_mfma_f32_16x16x32_bf16(kf0, qfl[0], z, 0, 0, 0);
                t = __builtin_amdgcn_mfma_f32_16x16x32_bf16(kf1, qfl[1], t, 0, 0, 0);
                pack_store(t, sP + (size_t)qg * 72 + kgb, kc == qtl, kgb, qg);
            }
        }
        // PV: O += P·V (wave reads only its own sP rows -> no extra barrier)
#pragma unroll
        for (int kb = 0; kb < 2; ++kb) {
            const bf16x8 pfh = *(const bf16x8*)(sP + (size_t)(64 + wave * 16 + l15) * 72 + kb * 32 + quad * 8);
#pragma unroll
            for (int nt = 0; nt < 4; ++nt) {
                const int cv = ((kb << 2) | quad) ^ swz;
                const bf16x8 vf = *(const bf16x8*)(sVb + (nt * 16 + l15) * 64 + cv * 8);
                acch[nt] = __builtin_amdgcn_mfma_f32_16x16x32_bf16(pfh, vf, acch[nt], 0, 0, 0);
                if (lact) {
                    const bf16x8 pfl = *(const bf16x8*)(sP + (size_t)(wave * 16 + l15) * 72 + kb * 32 + quad * 8);
                    accl[nt] = __builtin_amdgcn_mfma_f32_16x16x32_bf16(pfl, vf, accl[nt], 0, 0, 0);
                }
            }
        }
        __syncthreads();   // drains lgkm (reads of cur done) + vmcnt (stage kc+1 done)
    }
    // epilogue: write combined-head fp32 o [B,S,D] (full overwrite, no atomics)
#pragma unroll
    for (int nt = 0; nt < 4; ++nt) {
        const int col = hd * 64 + nt * 16 + l15;
        const int rl = qtl * 64 + wave * 16 + quad * 4;
        const int rh = qth * 64 + wave * 16 + quad * 4;
#pragma unroll
        for (int r = 0; r < 4; ++r) {
            o[(size_t)(b * 2048 + rl + r) * 1024 + col] = accl[nt][r];
            o[(size_t)(b * 2048 + rh + r) * 1024 + col] = acch[nt][r];
        }
    }
}

// ---------------------------------------------------------------------------
// Gated RMSNorm: one block per row of o [4096][1024] fp32 -> bf16
// ---------------------------------------------------------------------------
__global__ __launch_bounds__(256) void rms_gate(const float* __restrict__ o, const float* __restrict__ scale,
                                                const float* __restrict__ gate, u16* __restrict__ out) {
    const int row = blockIdx.x;
    const int tid = threadIdx.x;
    const floatx4* op = (const floatx4*)(o + (size_t)row * 1024);
    floatx4 v = op[tid];
    float ss = v[0] * v[0] + v[1] * v[1] + v[2] * v[2] + v[3] * v[3];
#pragma unroll
    for (int m = 32; m >= 1; m >>= 1) ss += __shfl_xor(ss, m, 64);
    __shared__ float red[4];
    if ((tid & 63) == 0) red[tid >> 6] = ss;
    __syncthreads();
    const float ms = (red[0] + red[1] + red[2] + red[3]) * (1.0f / 1024.0f);
    const float inv = rsqrtf(ms + 1e-7f);
    const int c = tid * 4;
#pragma unroll
    for (int j = 0; j < 4; ++j) {
        const float s = scale[c + j];
        const float g = gate[c + j];
        const float x = v[j];
        const float sig = 1.0f / (1.0f + __expf(-g * x));
        out[(size_t)row * 1024 + c + j] = f2bf(s * x * inv * sig);
    }
}

// ---------------------------------------------------------------------------
extern "C" void kernel_launch(void* const* d_in, const int* in_sizes, int n_in,
                              void* d_out, int out_size, void* d_ws, size_t ws_size,
                              hipStream_t stream) {
    const float* x     = (const float*)d_in[0];   // [2,2048,1024] fp32
    // d_in[1] = mem_mask: structurally causal, applied analytically
    const float* Wqkv  = (const float*)d_in[2];   // [1024,3072] fp32
    const float* Wout  = (const float*)d_in[3];   // [1024,1024] fp32
    const float* bout  = (const float*)d_in[4];   // [1024] fp32
    const float* scale = (const float*)d_in[5];   // [1024] fp32
    const float* gate  = (const float*)d_in[6];   // [1024] fp32
    float* out = (float*)d_out;                   // [2,2048,1024] fp32

    char* p = (char*)d_ws;
    u16* xb    = (u16*)p; p += (size_t)4096 * 1024 * 2;    // x in bf16
    u16* h     = (u16*)p; p += (size_t)4096 * 3072 * 2;    // qkv projection (bf16)
    u16* vt    = (u16*)p; p += (size_t)32 * 64 * 2048 * 2; // V^T [bh][dh][s], pre-scaled 0.125
    u16* WqkvT = (u16*)p; p += (size_t)3072 * 1024 * 2;
    u16* WoutT = (u16*)p; p += (size_t)1024 * 1024 * 2;
    float* oat = (float*)p; p += (size_t)4096 * 1024 * 4;  // attention out fp32
    u16* onorm = (u16*)p; p += (size_t)4096 * 1024 * 2;

    prep<<<8192, 256, 0, stream>>>(x, xb, Wqkv, WqkvT, Wout, WoutT);
    gemm_bt<128, false, u16, true><<<dim3(24, 32), 256, 0, stream>>>(xb, WqkvT, h, nullptr, vt, 4096, 3072, 1024);
    relu_attn<<<512, 256, 0, stream>>>(h, vt, oat);
    rms_gate<<<4096, 256, 0, stream>>>(oat, scale, gate, onorm);
    gemm_bt<64, true, float, false><<<dim3(8, 64), 256, 0, stream>>>(onorm, WoutT, out, bout, nullptr, 4096, 1024, 1024);
}